// Round 8
// baseline (110.951 us; speedup 1.0000x reference)
//
#include <hip/hip_runtime.h>
#include <hip/hip_bf16.h>
#include <math.h>

#define V_ 50000
#define E_ 256
#define H_ 256
#define B_ 64
#define S_ 2048
#define NCHK 32            // S/64 score chunks (global)

typedef __attribute__((ext_vector_type(4))) float f32x4;
typedef __attribute__((ext_vector_type(8))) __bf16 bf16x8;

static __device__ __forceinline__ f32x4 mfma16(bf16x8 a, bf16x8 b, f32x4 c) {
  return __builtin_amdgcn_mfma_f32_16x16x32_bf16(a, b, c, 0, 0, 0);
}
static __device__ __forceinline__ float fast_tanh(float x) {
  const float e2 = __expf(2.0f * x);
  return 1.0f - 2.0f / (e2 + 1.0f);
}

// ---------------- prep: xU = x@U ; xWih = x@W_ih^T + b_ih + b_hh ----------------
__global__ __launch_bounds__(256) void prep_k(
    const int* __restrict__ inp, const float* __restrict__ emb,
    const float* __restrict__ U, const float* __restrict__ W_ih,
    const float* __restrict__ b_ih, const float* __restrict__ b_hh,
    float* __restrict__ xU, float* __restrict__ xWih) {
  const int b = blockIdx.x, h = threadIdx.x;
  __shared__ float xs[H_];
  xs[h] = emb[(size_t)inp[b] * E_ + h];
  __syncthreads();
  float au = 0.f, aw = 0.f;
  const float* __restrict__ wir = W_ih + (size_t)h * E_;
  for (int k = 0; k < H_; k += 4) {
    const float4 x4 = *reinterpret_cast<const float4*>(&xs[k]);
    const float4 w4 = *reinterpret_cast<const float4*>(wir + k);
    aw = fmaf(x4.x, w4.x, aw); aw = fmaf(x4.y, w4.y, aw);
    aw = fmaf(x4.z, w4.z, aw); aw = fmaf(x4.w, w4.w, aw);
    au = fmaf(x4.x, U[(size_t)(k + 0) * H_ + h], au);
    au = fmaf(x4.y, U[(size_t)(k + 1) * H_ + h], au);
    au = fmaf(x4.z, U[(size_t)(k + 2) * H_ + h], au);
    au = fmaf(x4.w, U[(size_t)(k + 3) * H_ + h], au);
  }
  xU[b * H_ + h] = au;
  xWih[b * H_ + h] = aw + b_ih[h] + b_hh[h];
}

// ---------------- prep W: single SWIZZLED transposed bf16 table wt[n][k^((n&7)<<3)] ----------------
__global__ __launch_bounds__(256) void prep_w(
    const float* __restrict__ W, __bf16* __restrict__ wt) {
  const int idx = blockIdx.x * 256 + threadIdx.x;
  const int n = idx >> 8, k = idx & 255;
  wt[n * H_ + (k ^ ((n & 7) << 3))] = (__bf16)W[(size_t)k * H_ + n];
}

// ---------------- fused attention: barrier-free K-loop ----------------
// 512 thr, 8 waves = 4 row-groups x 2 col-groups. Strip = 128 s-rows.
// W: full 256x256 bf16 table resident in LDS (128 KB), staged once.
// A: per-lane direct global->reg f32x8, converted to hi/lo bf16 in-reg.
// NO __syncthreads anywhere in the K-loop; waves drift to hide latency.
__global__ __launch_bounds__(512) void attn_fused(
    const float* __restrict__ enc, const __bf16* __restrict__ wt,
    const float* __restrict__ xU, const float* __restrict__ vv,
    float* __restrict__ ctxp, float* __restrict__ mlout) {
  const int bx = blockIdx.x, b = blockIdx.y;
  const int t = threadIdx.x;
  const int w = t >> 6, l = t & 63, l15 = l & 15, lg = l >> 4;
  const int rg = w >> 1, cg = w & 1;

  __shared__ __bf16 Wl[H_ * H_];     // 128 KB
  __shared__ float ered[2][128];
  __shared__ float wgt[128];
  __shared__ float mlL[2][2];

  // stage swizzled W table: linear 16B copy (pre-swizzled in global)
  {
    const bf16x8* __restrict__ src = reinterpret_cast<const bf16x8*>(wt);
    bf16x8* dst = reinterpret_cast<bf16x8*>(Wl);
#pragma unroll
    for (int i = 0; i < 16; ++i) dst[i * 512 + t] = src[i * 512 + t];
  }
  __syncthreads();

  for (int si = 0; si < 2; ++si) {
    const int s0 = (bx * 2 + si) * 128;
    const float* __restrict__ encS = enc + ((size_t)b * S_ + s0) * H_;
    const float* __restrict__ a0 = encS + (size_t)(rg * 32 + l15) * H_ + lg * 8;
    const float* __restrict__ a1 = encS + (size_t)(rg * 32 + 16 + l15) * H_ + lg * 8;

    f32x4 acc[2][8];
#pragma unroll
    for (int rf = 0; rf < 2; ++rf)
#pragma unroll
      for (int cf = 0; cf < 8; ++cf) acc[rf][cf] = (f32x4)(0.f);

    float4 af[2][2][2];   // [buf][rf][half]
    af[0][0][0] = *reinterpret_cast<const float4*>(a0);
    af[0][0][1] = *reinterpret_cast<const float4*>(a0 + 4);
    af[0][1][0] = *reinterpret_cast<const float4*>(a1);
    af[0][1][1] = *reinterpret_cast<const float4*>(a1 + 4);

#pragma unroll
    for (int k = 0; k < 8; ++k) {
      const int cb = k & 1;
      // prefetch A for ksub k+1 (HBM; hidden under this ksub's MFMAs)
      if (k < 7) {
        af[cb ^ 1][0][0] = *reinterpret_cast<const float4*>(a0 + (k + 1) * 32);
        af[cb ^ 1][0][1] = *reinterpret_cast<const float4*>(a0 + (k + 1) * 32 + 4);
        af[cb ^ 1][1][0] = *reinterpret_cast<const float4*>(a1 + (k + 1) * 32);
        af[cb ^ 1][1][1] = *reinterpret_cast<const float4*>(a1 + (k + 1) * 32 + 4);
      }
      // B fragments from resident LDS (swizzled, conflict-free)
      bf16x8 bb[8];
#pragma unroll
      for (int cf = 0; cf < 8; ++cf) {
        const int col = cg * 128 + cf * 16 + l15;
        bb[cf] = *reinterpret_cast<const bf16x8*>(
            &Wl[col * H_ + ((k * 32 + lg * 8) ^ ((col & 7) << 3))]);
      }
      // convert A cur -> hi/lo planes
      bf16x8 ahi[2], alo[2];
#pragma unroll
      for (int rf = 0; rf < 2; ++rf) {
        const float xa[8] = {af[cb][rf][0].x, af[cb][rf][0].y, af[cb][rf][0].z, af[cb][rf][0].w,
                             af[cb][rf][1].x, af[cb][rf][1].y, af[cb][rf][1].z, af[cb][rf][1].w};
#pragma unroll
        for (int j = 0; j < 8; ++j) {
          const __bf16 hh = (__bf16)xa[j];
          ahi[rf][j] = hh;
          alo[rf][j] = (__bf16)(xa[j] - (float)hh);
        }
      }
      // 2rf x 8cf x 2 planes = 32 MFMA
#pragma unroll
      for (int rf = 0; rf < 2; ++rf)
#pragma unroll
        for (int cf = 0; cf < 8; ++cf) {
          acc[rf][cf] = mfma16(ahi[rf], bb[cf], acc[rf][cf]);
          acc[rf][cf] = mfma16(alo[rf], bb[cf], acc[rf][cf]);
        }
    }

    // ---- epilogue: tanh + v-dot + 16-lane reduce ----
    float part[2][4];
#pragma unroll
    for (int rf = 0; rf < 2; ++rf)
#pragma unroll
      for (int reg = 0; reg < 4; ++reg) part[rf][reg] = 0.f;
#pragma unroll
    for (int cf = 0; cf < 8; ++cf) {
      const int col = cg * 128 + cf * 16 + l15;
      const float xu = xU[b * H_ + col];
      const float vw = vv[col];
#pragma unroll
      for (int rf = 0; rf < 2; ++rf)
#pragma unroll
        for (int reg = 0; reg < 4; ++reg)
          part[rf][reg] += fast_tanh(xu + acc[rf][cf][reg]) * vw;
    }
#pragma unroll
    for (int o = 1; o < 16; o <<= 1)
#pragma unroll
      for (int rf = 0; rf < 2; ++rf)
#pragma unroll
        for (int reg = 0; reg < 4; ++reg)
          part[rf][reg] += __shfl_xor(part[rf][reg], o);
    if (l15 == 0) {
#pragma unroll
      for (int rf = 0; rf < 2; ++rf)
#pragma unroll
        for (int reg = 0; reg < 4; ++reg)
          ered[cg][rg * 32 + rf * 16 + lg * 4 + reg] = part[rf][reg];
    }
    __syncthreads();

    // per-64-row-chunk softmax stats (2 chunks per strip; one wave each)
    if (t < 128) {
      const float es = ered[0][t] + ered[1][t];
      float m = es;
#pragma unroll
      for (int o = 1; o < 64; o <<= 1) m = fmaxf(m, __shfl_xor(m, o));
      const float we = __expf(es - m);
      float ls = we;
#pragma unroll
      for (int o = 1; o < 64; o <<= 1) ls += __shfl_xor(ls, o);
      wgt[t] = we;
      if ((t & 63) == 0) { mlL[t >> 6][0] = m; mlL[t >> 6][1] = ls; }
    }
    __syncthreads();

    // ctx partials: coalesced L2 re-read of own strip
    {
      const int c2 = t >> 8, h = t & 255;
      const float* __restrict__ ep = encS + (size_t)(c2 * 64) * H_ + h;
      float a = 0.f;
#pragma unroll 8
      for (int s = 0; s < 64; ++s) a = fmaf(wgt[c2 * 64 + s], ep[(size_t)s * H_], a);
      ctxp[((size_t)(bx * 4 + si * 2 + c2) * B_ + b) * H_ + h] = a;
    }
    if ((t & 255) == 0) {
      const int c2 = t >> 8;
      mlout[((bx * 4 + si * 2 + c2) * B_ + b) * 2 + 0] = mlL[c2][0];
      mlout[((bx * 4 + si * 2 + c2) * B_ + b) * 2 + 1] = mlL[c2][1];
    }
    __syncthreads();   // ered/wgt reuse in next strip
  }
}

// ---------------- flash combine + h_new GEMV ----------------
__global__ __launch_bounds__(256) void combine_hnew(
    const float* __restrict__ ctxp, const float* __restrict__ mlout,
    const float* __restrict__ xWih, const float* __restrict__ W_hh,
    float* __restrict__ out_h, __bf16* __restrict__ hn) {
  const int b = blockIdx.x, h = threadIdx.x;
  __shared__ float cs[H_];
  float M = -3.4e38f;
#pragma unroll
  for (int cc = 0; cc < NCHK; ++cc) M = fmaxf(M, mlout[(cc * B_ + b) * 2]);
  float num = 0.f, den = 0.f;
#pragma unroll
  for (int cc = 0; cc < NCHK; ++cc) {
    const float mw = __expf(mlout[(cc * B_ + b) * 2] - M);
    den = fmaf(mw, mlout[(cc * B_ + b) * 2 + 1], den);
    num = fmaf(mw, ctxp[((size_t)cc * B_ + b) * H_ + h], num);
  }
  cs[h] = num / den;
  __syncthreads();
  const float* __restrict__ wr = W_hh + (size_t)h * H_;
  float a = xWih[b * H_ + h];
  for (int k = 0; k < H_; k += 4) {
    const float4 w4 = *reinterpret_cast<const float4*>(wr + k);
    const float4 c4 = *reinterpret_cast<const float4*>(&cs[k]);
    a = fmaf(c4.x, w4.x, a); a = fmaf(c4.y, w4.y, a);
    a = fmaf(c4.z, w4.z, a); a = fmaf(c4.w, w4.w, a);
  }
  const float hv = fast_tanh(a);
  out_h[b * H_ + h] = hv;
  hn[b * H_ + h] = (__bf16)hv;
}

// ---------------- logits = h_new @ W_out^T + b_out via pure-bf16 MFMA ----------------
__global__ __launch_bounds__(256) void logits_mfma(
    const float* __restrict__ Wout, const float* __restrict__ bout,
    const __bf16* __restrict__ hn, float* __restrict__ logits) {
  const int v0 = blockIdx.x * 64;
  const int t = threadIdx.x;
  const int wv = t >> 6, l = t & 63, l15 = l & 15, lg = l >> 4;

  __shared__ __bf16 Wsub[8][64][32];   // 32 KB, slot-rotated layout

  {
    const int srow = t >> 2, sg = t & 3;
    const int wslot = (sg + (srow >> 1)) & 3;
    const int vc = (v0 + srow) < V_ ? (v0 + srow) : (V_ - 1);
    const float* __restrict__ wr = Wout + (size_t)vc * H_ + sg * 8;
#pragma unroll
    for (int ks = 0; ks < 8; ++ks) {
      const float4 f0 = *reinterpret_cast<const float4*>(wr + ks * 32);
      const float4 f1 = *reinterpret_cast<const float4*>(wr + ks * 32 + 4);
      const float xv[8] = {f0.x, f0.y, f0.z, f0.w, f1.x, f1.y, f1.z, f1.w};
      bf16x8 h8;
#pragma unroll
      for (int j = 0; j < 8; ++j) h8[j] = (__bf16)xv[j];
      *reinterpret_cast<bf16x8*>(&Wsub[ks][srow][wslot * 8]) = h8;
    }
  }
  __syncthreads();

  f32x4 acc[4];
#pragma unroll
  for (int i = 0; i < 4; ++i) acc[i] = (f32x4)(0.f);
  const int colb = wv * 16 + l15;   // batch col
#pragma unroll
  for (int k = 0; k < 8; ++k) {
    const bf16x8 bfrag = *reinterpret_cast<const bf16x8*>(hn + (size_t)colb * H_ + k * 32 + lg * 8);
    bf16x8 ah[4];
#pragma unroll
    for (int rf = 0; rf < 4; ++rf) {
      const int rr = rf * 16 + l15;
      const int slot = (lg + (rr >> 1)) & 3;
      ah[rf] = *reinterpret_cast<const bf16x8*>(&Wsub[k][rr][slot * 8]);
    }
#pragma unroll
    for (int rf = 0; rf < 4; ++rf)
      acc[rf] = mfma16(ah[rf], bfrag, acc[rf]);
  }
#pragma unroll
  for (int rf = 0; rf < 4; ++rf) {
    const int v = v0 + rf * 16 + lg * 4;
    if (v < V_) {
      const float4 bo = *reinterpret_cast<const float4*>(bout + v);
      float4 o;
      o.x = acc[rf][0] + bo.x; o.y = acc[rf][1] + bo.y;
      o.z = acc[rf][2] + bo.z; o.w = acc[rf][3] + bo.w;
      *reinterpret_cast<float4*>(logits + (size_t)colb * V_ + v) = o;
    }
  }
}

extern "C" void kernel_launch(void* const* d_in, const int* in_sizes, int n_in,
                              void* d_out, int out_size, void* d_ws, size_t ws_size,
                              hipStream_t stream) {
  const int*   inp  = (const int*)  d_in[0];
  const float* enc  = (const float*)d_in[2];
  const float* emb  = (const float*)d_in[3];
  const float* U    = (const float*)d_in[4];
  const float* W    = (const float*)d_in[5];
  const float* v    = (const float*)d_in[6];
  const float* W_ih = (const float*)d_in[7];
  const float* W_hh = (const float*)d_in[8];
  const float* b_ih = (const float*)d_in[9];
  const float* b_hh = (const float*)d_in[10];
  const float* Wout = (const float*)d_in[11];
  const float* bout = (const float*)d_in[12];

  float* logits = (float*)d_out;
  float* out_h  = logits + (size_t)B_ * V_;

  float* ws    = (float*)d_ws;
  __bf16* wt   = (__bf16*)ws;                       // H*H bf16 (swizzled) = 128 KB
  float* xU    = ws + 32768;                        // after 128 KB
  float* xWih  = xU + B_ * H_;
  float* ctxp  = xWih + B_ * H_;                    // NCHK*B*H
  float* mlout = ctxp + (size_t)NCHK * B_ * H_;     // NCHK*B*2
  __bf16* hn   = (__bf16*)(mlout + NCHK * B_ * 2);  // B*H bf16

  prep_k<<<dim3(B_), dim3(256), 0, stream>>>(inp, emb, U, W_ih, b_ih, b_hh, xU, xWih);
  prep_w<<<dim3(H_ * H_ / 256), dim3(256), 0, stream>>>(W, wt);
  attn_fused<<<dim3(8, B_), dim3(512), 0, stream>>>(enc, wt, xU, v, ctxp, mlout);
  combine_hnew<<<dim3(B_), dim3(256), 0, stream>>>(ctxp, mlout, xWih, W_hh, out_h, hn);
  logits_mfma<<<dim3((V_ + 63) / 64), dim3(256), 0, stream>>>(Wout, bout, hn, logits);
}

// Round 9
// 110.860 us; speedup vs baseline: 1.0008x; 1.0008x over previous
//
#include <hip/hip_runtime.h>
#include <hip/hip_bf16.h>
#include <math.h>

#define V_ 50000
#define E_ 256
#define H_ 256
#define B_ 64
#define S_ 2048
#define NCHK 32            // S/64 score chunks (global)

typedef __attribute__((ext_vector_type(4))) float f32x4;
typedef __attribute__((ext_vector_type(16))) float f32x16;
typedef __attribute__((ext_vector_type(8))) __bf16 bf16x8;

static __device__ __forceinline__ f32x4 mfma16(bf16x8 a, bf16x8 b, f32x4 c) {
  return __builtin_amdgcn_mfma_f32_16x16x32_bf16(a, b, c, 0, 0, 0);
}
static __device__ __forceinline__ f32x16 mfma32(bf16x8 a, bf16x8 b, f32x16 c) {
  return __builtin_amdgcn_mfma_f32_32x32x16_bf16(a, b, c, 0, 0, 0);
}
static __device__ __forceinline__ float fast_tanh(float x) {
  const float e2 = __expf(2.0f * x);
  return 1.0f - 2.0f / (e2 + 1.0f);
}

// ---------------- prep: xU = x@U ; xWih = x@W_ih^T + b_ih + b_hh ----------------
__global__ __launch_bounds__(256) void prep_k(
    const int* __restrict__ inp, const float* __restrict__ emb,
    const float* __restrict__ U, const float* __restrict__ W_ih,
    const float* __restrict__ b_ih, const float* __restrict__ b_hh,
    float* __restrict__ xU, float* __restrict__ xWih) {
  const int b = blockIdx.x, h = threadIdx.x;
  __shared__ float xs[H_];
  xs[h] = emb[(size_t)inp[b] * E_ + h];
  __syncthreads();
  float au = 0.f, aw = 0.f;
  const float* __restrict__ wir = W_ih + (size_t)h * E_;
  for (int k = 0; k < H_; k += 4) {
    const float4 x4 = *reinterpret_cast<const float4*>(&xs[k]);
    const float4 w4 = *reinterpret_cast<const float4*>(wir + k);
    aw = fmaf(x4.x, w4.x, aw); aw = fmaf(x4.y, w4.y, aw);
    aw = fmaf(x4.z, w4.z, aw); aw = fmaf(x4.w, w4.w, aw);
    au = fmaf(x4.x, U[(size_t)(k + 0) * H_ + h], au);
    au = fmaf(x4.y, U[(size_t)(k + 1) * H_ + h], au);
    au = fmaf(x4.z, U[(size_t)(k + 2) * H_ + h], au);
    au = fmaf(x4.w, U[(size_t)(k + 3) * H_ + h], au);
  }
  xU[b * H_ + h] = au;
  xWih[b * H_ + h] = aw + b_ih[h] + b_hh[h];
}

// ---------------- prep W: bf16 table wt2[k>>3][col][k&7] (koct-major, col contiguous) ----------------
__global__ __launch_bounds__(256) void prep_w(
    const float* __restrict__ W, __bf16* __restrict__ wt2) {
  const int idx = blockIdx.x * 256 + threadIdx.x;   // 65536 elements
  const int k = idx >> 8, col = idx & 255;
  wt2[((size_t)(k >> 3) * 256 + col) * 8 + (k & 7)] = (__bf16)W[(size_t)k * H_ + col];
}

// ---------------- fused attention: 32x32x16 MFMA, wave = 32 rows x 256 cols ----------------
// 512 thr (8 waves), 1 block/CU. W resident in LDS (128 KB), staged once per block.
// A: enc hi/lo from per-lane global f32 loads (dist-1 dbuf). Barrier-free K-loop.
// Per K-step/wave: 16 MFMA (512 SIMD-cyc) vs ~80 cyc overhead -> ~86% per-wave MFMA duty.
__global__ __launch_bounds__(512, 2) void attn_fused(
    const float* __restrict__ enc, const __bf16* __restrict__ wt2,
    const float* __restrict__ xU, const float* __restrict__ vv,
    float* __restrict__ ctxp, float* __restrict__ mlout) {
  const int t = threadIdx.x;
  const int w = t >> 6, l = t & 63, l31 = l & 31, h5 = l >> 5;

  __shared__ __bf16 Wl[32 * 256 * 8];   // 128 KB: [koct][col][8]
  __shared__ float ered[256];
  __shared__ float wgt[4][64];
  __shared__ float mlL[4][2];

  // stage W table once (linear 16B copy)
  {
    const bf16x8* __restrict__ src = reinterpret_cast<const bf16x8*>(wt2);
    bf16x8* dst = reinterpret_cast<bf16x8*>(Wl);
#pragma unroll
    for (int i = 0; i < 16; ++i) dst[i * 512 + t] = src[i * 512 + t];
  }
  // per-lane col-dependent epilogue constants (col = cf*32 + l31)
  float xu[8], vw[8];
  __syncthreads();

#pragma unroll 1
  for (int uu = 0; uu < 2; ++uu) {
    const int unit = blockIdx.x * 2 + uu;
    const int b = unit >> 3;          // batch
    const int sidx = unit & 7;        // 256-row strip within batch
    const int s0 = sidx * 256;

    const float* __restrict__ encA =
        enc + ((size_t)b * S_ + s0 + w * 32 + l31) * H_ + h5 * 8;

    f32x16 acc[8];
#pragma unroll
    for (int cf = 0; cf < 8; ++cf) acc[cf] = (f32x16)(0.f);

    float4 af[2][2];
    af[0][0] = *reinterpret_cast<const float4*>(encA);
    af[0][1] = *reinterpret_cast<const float4*>(encA + 4);

#pragma unroll
    for (int ks = 0; ks < 16; ++ks) {
      const int cb = ks & 1;
      // prefetch A for kstep ks+1 (hidden under this step's 512 cyc of MFMA)
      if (ks < 15) {
        af[cb ^ 1][0] = *reinterpret_cast<const float4*>(encA + (ks + 1) * 16);
        af[cb ^ 1][1] = *reinterpret_cast<const float4*>(encA + (ks + 1) * 16 + 4);
      }
      // B fragments: 32 lanes read 512B CONTIGUOUS per half (conflict-free b128)
      bf16x8 bb[8];
      const int koct = ks * 2 + h5;
#pragma unroll
      for (int cf = 0; cf < 8; ++cf)
        bb[cf] = *reinterpret_cast<const bf16x8*>(
            &Wl[((size_t)koct * 256 + cf * 32 + l31) * 8]);
      // convert A -> hi/lo planes
      bf16x8 ahi, alo;
      {
        const float xa[8] = {af[cb][0].x, af[cb][0].y, af[cb][0].z, af[cb][0].w,
                             af[cb][1].x, af[cb][1].y, af[cb][1].z, af[cb][1].w};
#pragma unroll
        for (int j = 0; j < 8; ++j) {
          const __bf16 hh = (__bf16)xa[j];
          ahi[j] = hh;
          alo[j] = (__bf16)(xa[j] - (float)hh);
        }
      }
      // 8 hi-MFMAs then 8 lo-MFMAs (lo depends on hi 8 issues later -> no stall)
#pragma unroll
      for (int cf = 0; cf < 8; ++cf) acc[cf] = mfma32(ahi, bb[cf], acc[cf]);
#pragma unroll
      for (int cf = 0; cf < 8; ++cf) acc[cf] = mfma32(alo, bb[cf], acc[cf]);
    }

    // ---- epilogue: tanh + v-dot; wave owns ALL cols -> row-sum needs only 32-lane reduce ----
#pragma unroll
    for (int cf = 0; cf < 8; ++cf) {
      const int col = cf * 32 + l31;
      xu[cf] = xU[b * H_ + col];
      vw[cf] = vv[col];
    }
    float rs[16];
#pragma unroll
    for (int reg = 0; reg < 16; ++reg) {
      float s = 0.f;
#pragma unroll
      for (int cf = 0; cf < 8; ++cf)
        s += fast_tanh(xu[cf] + acc[cf][reg]) * vw[cf];
      rs[reg] = s;
    }
#pragma unroll
    for (int o = 1; o < 32; o <<= 1)
#pragma unroll
      for (int reg = 0; reg < 16; ++reg)
        rs[reg] += __shfl_xor(rs[reg], o);
    if (l31 == 0) {
#pragma unroll
      for (int reg = 0; reg < 16; ++reg)
        ered[w * 32 + (reg & 3) + 8 * (reg >> 2) + 4 * h5] = rs[reg];
    }
    __syncthreads();

    // ---- per-64-row softmax stats: waves 0-3, one chunk each ----
    if (t < 256) {
      const int cidx = t >> 6, rr = t & 63;
      const float es = ered[cidx * 64 + rr];
      float m = es;
#pragma unroll
      for (int o = 1; o < 64; o <<= 1) m = fmaxf(m, __shfl_xor(m, o));
      const float we = __expf(es - m);
      float ls = we;
#pragma unroll
      for (int o = 1; o < 64; o <<= 1) ls += __shfl_xor(ls, o);
      wgt[cidx][rr] = we;
      if (rr == 0) { mlL[cidx][0] = m; mlL[cidx][1] = ls; }
    }
    __syncthreads();

    // ---- ctx partials: coalesced L3 re-read of own strip ----
#pragma unroll
    for (int it = 0; it < 2; ++it) {
      const int cc = (t >> 8) + it * 2;   // chunk 0..3
      const int h = t & 255;
      const float* __restrict__ ep = enc + ((size_t)b * S_ + s0 + cc * 64) * H_ + h;
      float a = 0.f;
#pragma unroll 8
      for (int s = 0; s < 64; ++s) a = fmaf(wgt[cc][s], ep[(size_t)s * H_], a);
      ctxp[((size_t)(sidx * 4 + cc) * B_ + b) * H_ + h] = a;
    }
    if (t < 8) {
      const int cc = t >> 1;
      mlout[((sidx * 4 + cc) * B_ + b) * 2 + (t & 1)] = mlL[cc][t & 1];
    }
    __syncthreads();   // ered/wgt reuse in next unit
  }
}

// ---------------- flash combine + h_new GEMV ----------------
__global__ __launch_bounds__(256) void combine_hnew(
    const float* __restrict__ ctxp, const float* __restrict__ mlout,
    const float* __restrict__ xWih, const float* __restrict__ W_hh,
    float* __restrict__ out_h, __bf16* __restrict__ hn) {
  const int b = blockIdx.x, h = threadIdx.x;
  __shared__ float cs[H_];
  float M = -3.4e38f;
#pragma unroll
  for (int cc = 0; cc < NCHK; ++cc) M = fmaxf(M, mlout[(cc * B_ + b) * 2]);
  float num = 0.f, den = 0.f;
#pragma unroll
  for (int cc = 0; cc < NCHK; ++cc) {
    const float mw = __expf(mlout[(cc * B_ + b) * 2] - M);
    den = fmaf(mw, mlout[(cc * B_ + b) * 2 + 1], den);
    num = fmaf(mw, ctxp[((size_t)cc * B_ + b) * H_ + h], num);
  }
  cs[h] = num / den;
  __syncthreads();
  const float* __restrict__ wr = W_hh + (size_t)h * H_;
  float a = xWih[b * H_ + h];
  for (int k = 0; k < H_; k += 4) {
    const float4 w4 = *reinterpret_cast<const float4*>(wr + k);
    const float4 c4 = *reinterpret_cast<const float4*>(&cs[k]);
    a = fmaf(c4.x, w4.x, a); a = fmaf(c4.y, w4.y, a);
    a = fmaf(c4.z, w4.z, a); a = fmaf(c4.w, w4.w, a);
  }
  const float hv = fast_tanh(a);
  out_h[b * H_ + h] = hv;
  hn[b * H_ + h] = (__bf16)hv;
}

// ---------------- logits = h_new @ W_out^T + b_out via pure-bf16 MFMA ----------------
__global__ __launch_bounds__(256) void logits_mfma(
    const float* __restrict__ Wout, const float* __restrict__ bout,
    const __bf16* __restrict__ hn, float* __restrict__ logits) {
  const int v0 = blockIdx.x * 64;
  const int t = threadIdx.x;
  const int wv = t >> 6, l = t & 63, l15 = l & 15, lg = l >> 4;

  __shared__ __bf16 Wsub[8][64][32];   // 32 KB, slot-rotated layout

  {
    const int srow = t >> 2, sg = t & 3;
    const int wslot = (sg + (srow >> 1)) & 3;
    const int vc = (v0 + srow) < V_ ? (v0 + srow) : (V_ - 1);
    const float* __restrict__ wr = Wout + (size_t)vc * H_ + sg * 8;
#pragma unroll
    for (int ks = 0; ks < 8; ++ks) {
      const float4 f0 = *reinterpret_cast<const float4*>(wr + ks * 32);
      const float4 f1 = *reinterpret_cast<const float4*>(wr + ks * 32 + 4);
      const float xv[8] = {f0.x, f0.y, f0.z, f0.w, f1.x, f1.y, f1.z, f1.w};
      bf16x8 h8;
#pragma unroll
      for (int j = 0; j < 8; ++j) h8[j] = (__bf16)xv[j];
      *reinterpret_cast<bf16x8*>(&Wsub[ks][srow][wslot * 8]) = h8;
    }
  }
  __syncthreads();

  f32x4 acc[4];
#pragma unroll
  for (int i = 0; i < 4; ++i) acc[i] = (f32x4)(0.f);
  const int colb = wv * 16 + l15;   // batch col
#pragma unroll
  for (int k = 0; k < 8; ++k) {
    const bf16x8 bfrag = *reinterpret_cast<const bf16x8*>(hn + (size_t)colb * H_ + k * 32 + lg * 8);
    bf16x8 ah[4];
#pragma unroll
    for (int rf = 0; rf < 4; ++rf) {
      const int rr = rf * 16 + l15;
      const int slot = (lg + (rr >> 1)) & 3;
      ah[rf] = *reinterpret_cast<const bf16x8*>(&Wsub[k][rr][slot * 8]);
    }
#pragma unroll
    for (int rf = 0; rf < 4; ++rf)
      acc[rf] = mfma16(ah[rf], bfrag, acc[rf]);
  }
#pragma unroll
  for (int rf = 0; rf < 4; ++rf) {
    const int v = v0 + rf * 16 + lg * 4;
    if (v < V_) {
      const float4 bo = *reinterpret_cast<const float4*>(bout + v);
      float4 o;
      o.x = acc[rf][0] + bo.x; o.y = acc[rf][1] + bo.y;
      o.z = acc[rf][2] + bo.z; o.w = acc[rf][3] + bo.w;
      *reinterpret_cast<float4*>(logits + (size_t)colb * V_ + v) = o;
    }
  }
}

extern "C" void kernel_launch(void* const* d_in, const int* in_sizes, int n_in,
                              void* d_out, int out_size, void* d_ws, size_t ws_size,
                              hipStream_t stream) {
  const int*   inp  = (const int*)  d_in[0];
  const float* enc  = (const float*)d_in[2];
  const float* emb  = (const float*)d_in[3];
  const float* U    = (const float*)d_in[4];
  const float* W    = (const float*)d_in[5];
  const float* v    = (const float*)d_in[6];
  const float* W_ih = (const float*)d_in[7];
  const float* W_hh = (const float*)d_in[8];
  const float* b_ih = (const float*)d_in[9];
  const float* b_hh = (const float*)d_in[10];
  const float* Wout = (const float*)d_in[11];
  const float* bout = (const float*)d_in[12];

  float* logits = (float*)d_out;
  float* out_h  = logits + (size_t)B_ * V_;

  float* ws    = (float*)d_ws;
  __bf16* wt2  = (__bf16*)ws;                       // 65536 bf16 = 128 KB
  float* xU    = ws + 32768;                        // after 128 KB
  float* xWih  = xU + B_ * H_;
  float* ctxp  = xWih + B_ * H_;                    // NCHK*B*H
  float* mlout = ctxp + (size_t)NCHK * B_ * H_;     // NCHK*B*2
  __bf16* hn   = (__bf16*)(mlout + NCHK * B_ * 2);  // B*H bf16

  prep_k<<<dim3(B_), dim3(256), 0, stream>>>(inp, emb, U, W_ih, b_ih, b_hh, xU, xWih);
  prep_w<<<dim3(H_ * H_ / 256), dim3(256), 0, stream>>>(W, wt2);
  attn_fused<<<dim3(256), dim3(512), 0, stream>>>(enc, wt2, xU, v, ctxp, mlout);
  combine_hnew<<<dim3(B_), dim3(256), 0, stream>>>(ctxp, mlout, xWih, W_hh, out_h, hn);
  logits_mfma<<<dim3((V_ + 63) / 64), dim3(256), 0, stream>>>(Wout, bout, hn, logits);
}

// Round 11
// 110.787 us; speedup vs baseline: 1.0015x; 1.0007x over previous
//
#include <hip/hip_runtime.h>
#include <hip/hip_bf16.h>
#include <math.h>

#define V_ 50000
#define E_ 256
#define H_ 256
#define B_ 64
#define S_ 2048
#define NCHK 32            // S/64 score chunks (global)

typedef __attribute__((ext_vector_type(4))) float f32x4;
typedef __attribute__((ext_vector_type(16))) float f32x16;
typedef __attribute__((ext_vector_type(8))) __bf16 bf16x8;

static __device__ __forceinline__ f32x4 mfma16(bf16x8 a, bf16x8 b, f32x4 c) {
  return __builtin_amdgcn_mfma_f32_16x16x32_bf16(a, b, c, 0, 0, 0);
}
static __device__ __forceinline__ f32x16 mfma32(bf16x8 a, bf16x8 b, f32x16 c) {
  return __builtin_amdgcn_mfma_f32_32x32x16_bf16(a, b, c, 0, 0, 0);
}
static __device__ __forceinline__ float fast_tanh(float x) {
  const float e2 = __expf(2.0f * x);
  return 1.0f - 2.0f / (e2 + 1.0f);
}

// ---------------- prep: xU = x@U ; xWih = x@W_ih^T + b_ih + b_hh ----------------
__global__ __launch_bounds__(256) void prep_k(
    const int* __restrict__ inp, const float* __restrict__ emb,
    const float* __restrict__ U, const float* __restrict__ W_ih,
    const float* __restrict__ b_ih, const float* __restrict__ b_hh,
    float* __restrict__ xU, float* __restrict__ xWih) {
  const int b = blockIdx.x, h = threadIdx.x;
  __shared__ float xs[H_];
  xs[h] = emb[(size_t)inp[b] * E_ + h];
  __syncthreads();
  float au = 0.f, aw = 0.f;
  const float* __restrict__ wir = W_ih + (size_t)h * E_;
  for (int k = 0; k < H_; k += 4) {
    const float4 x4 = *reinterpret_cast<const float4*>(&xs[k]);
    const float4 w4 = *reinterpret_cast<const float4*>(wir + k);
    aw = fmaf(x4.x, w4.x, aw); aw = fmaf(x4.y, w4.y, aw);
    aw = fmaf(x4.z, w4.z, aw); aw = fmaf(x4.w, w4.w, aw);
    au = fmaf(x4.x, U[(size_t)(k + 0) * H_ + h], au);
    au = fmaf(x4.y, U[(size_t)(k + 1) * H_ + h], au);
    au = fmaf(x4.z, U[(size_t)(k + 2) * H_ + h], au);
    au = fmaf(x4.w, U[(size_t)(k + 3) * H_ + h], au);
  }
  xU[b * H_ + h] = au;
  xWih[b * H_ + h] = aw + b_ih[h] + b_hh[h];
}

// ---------------- prep W: bf16 table wt2[k>>3][col][k&7] (koct-major, col contiguous) ----------------
__global__ __launch_bounds__(256) void prep_w(
    const float* __restrict__ W, __bf16* __restrict__ wt2) {
  const int idx = blockIdx.x * 256 + threadIdx.x;   // 65536 elements
  const int k = idx >> 8, col = idx & 255;
  wt2[((size_t)(k >> 3) * 256 + col) * 8 + (k & 7)] = (__bf16)W[(size_t)k * H_ + col];
}

// ---------------- fused attention: 32x32x16 MFMA, wave = 32 rows x 256 cols ----------------
// 512 thr (8 waves), 1 block/CU. W resident in LDS (128 KB). Barrier-free K-loop.
// A: depth-4 global prefetch ring (covers ~900cy HBM miss latency).
// B: depth-2 LDS double-buffer (covers ~120cy ds_read latency).
// Loop body order (bug in R10 fixed): convert af[ca] -> refill af[ca](ks+4)
// -> B-prefetch(ks+1) -> 16 MFMAs.
__global__ __launch_bounds__(512, 2) void attn_fused(
    const float* __restrict__ enc, const __bf16* __restrict__ wt2,
    const float* __restrict__ xU, const float* __restrict__ vv,
    float* __restrict__ ctxp, float* __restrict__ mlout) {
  const int t = threadIdx.x;
  const int w = t >> 6, l = t & 63, l31 = l & 31, h5 = l >> 5;

  __shared__ __bf16 Wl[32 * 256 * 8];   // 128 KB: [koct][col][8]
  __shared__ float ered[256];
  __shared__ float wgt[4][64];
  __shared__ float mlL[4][2];

  // stage W table once (linear 16B copy)
  {
    const bf16x8* __restrict__ src = reinterpret_cast<const bf16x8*>(wt2);
    bf16x8* dst = reinterpret_cast<bf16x8*>(Wl);
#pragma unroll
    for (int i = 0; i < 16; ++i) dst[i * 512 + t] = src[i * 512 + t];
  }
  float xu[8], vw[8];
  __syncthreads();

#pragma unroll 1
  for (int uu = 0; uu < 2; ++uu) {
    const int unit = blockIdx.x * 2 + uu;
    const int b = unit >> 3;          // batch
    const int sidx = unit & 7;        // 256-row strip within batch
    const int s0 = sidx * 256;

    const float* __restrict__ encA =
        enc + ((size_t)b * S_ + s0 + w * 32 + l31) * H_ + h5 * 8;

    f32x16 acc[8];
#pragma unroll
    for (int cf = 0; cf < 8; ++cf) acc[cf] = (f32x16)(0.f);

    // depth-4 A prefetch ring
    float4 af[4][2];
#pragma unroll
    for (int p = 0; p < 4; ++p) {
      af[p][0] = *reinterpret_cast<const float4*>(encA + p * 16);
      af[p][1] = *reinterpret_cast<const float4*>(encA + p * 16 + 4);
    }
    // depth-2 B LDS double-buffer
    bf16x8 bb[2][8];
#pragma unroll
    for (int cf = 0; cf < 8; ++cf)
      bb[0][cf] = *reinterpret_cast<const bf16x8*>(
          &Wl[((size_t)h5 * 256 + cf * 32 + l31) * 8]);

#pragma unroll
    for (int ks = 0; ks < 16; ++ks) {
      const int ca = ks & 3;
      const int pb = ks & 1;
      // 1) convert A(ks) -> hi/lo planes (consumes ring slot ca)
      bf16x8 ahi, alo;
      {
        const float4 c0 = af[ca][0], c1 = af[ca][1];
        const float xa[8] = {c0.x, c0.y, c0.z, c0.w, c1.x, c1.y, c1.z, c1.w};
#pragma unroll
        for (int j = 0; j < 8; ++j) {
          const __bf16 hh = (__bf16)xa[j];
          ahi[j] = hh;
          alo[j] = (__bf16)(xa[j] - (float)hh);
        }
      }
      // 2) refill ring slot ca with ks+4 (safe: consumed above)
      if (ks < 12) {
        af[ca][0] = *reinterpret_cast<const float4*>(encA + (ks + 4) * 16);
        af[ca][1] = *reinterpret_cast<const float4*>(encA + (ks + 4) * 16 + 4);
      }
      // 3) B prefetch for ks+1 into other buffer
      if (ks < 15) {
        const int koct = (ks + 1) * 2 + h5;
#pragma unroll
        for (int cf = 0; cf < 8; ++cf)
          bb[pb ^ 1][cf] = *reinterpret_cast<const bf16x8*>(
              &Wl[((size_t)koct * 256 + cf * 32 + l31) * 8]);
      }
      // 4) 16 MFMAs on current B buffer
#pragma unroll
      for (int cf = 0; cf < 8; ++cf) acc[cf] = mfma32(ahi, bb[pb][cf], acc[cf]);
#pragma unroll
      for (int cf = 0; cf < 8; ++cf) acc[cf] = mfma32(alo, bb[pb][cf], acc[cf]);
    }

    // ---- epilogue: tanh + v-dot; 32-lane reduce ----
#pragma unroll
    for (int cf = 0; cf < 8; ++cf) {
      const int col = cf * 32 + l31;
      xu[cf] = xU[b * H_ + col];
      vw[cf] = vv[col];
    }
    float rs[16];
#pragma unroll
    for (int reg = 0; reg < 16; ++reg) {
      float s = 0.f;
#pragma unroll
      for (int cf = 0; cf < 8; ++cf)
        s += fast_tanh(xu[cf] + acc[cf][reg]) * vw[cf];
      rs[reg] = s;
    }
#pragma unroll
    for (int o = 1; o < 32; o <<= 1)
#pragma unroll
      for (int reg = 0; reg < 16; ++reg)
        rs[reg] += __shfl_xor(rs[reg], o);
    if (l31 == 0) {
#pragma unroll
      for (int reg = 0; reg < 16; ++reg)
        ered[w * 32 + (reg & 3) + 8 * (reg >> 2) + 4 * h5] = rs[reg];
    }
    __syncthreads();

    // ---- per-64-row softmax stats: waves 0-3, one chunk each ----
    if (t < 256) {
      const int cidx = t >> 6, rr = t & 63;
      const float es = ered[cidx * 64 + rr];
      float m = es;
#pragma unroll
      for (int o = 1; o < 64; o <<= 1) m = fmaxf(m, __shfl_xor(m, o));
      const float we = __expf(es - m);
      float ls = we;
#pragma unroll
      for (int o = 1; o < 64; o <<= 1) ls += __shfl_xor(ls, o);
      wgt[cidx][rr] = we;
      if (rr == 0) { mlL[cidx][0] = m; mlL[cidx][1] = ls; }
    }
    __syncthreads();

    // ---- ctx partials: coalesced re-read of own strip (cache-warm) ----
#pragma unroll
    for (int it = 0; it < 2; ++it) {
      const int cc = (t >> 8) + it * 2;   // chunk 0..3
      const int h = t & 255;
      const float* __restrict__ ep = enc + ((size_t)b * S_ + s0 + cc * 64) * H_ + h;
      float a = 0.f;
#pragma unroll 8
      for (int s = 0; s < 64; ++s) a = fmaf(wgt[cc][s], ep[(size_t)s * H_], a);
      ctxp[((size_t)(sidx * 4 + cc) * B_ + b) * H_ + h] = a;
    }
    if (t < 8) {
      const int cc = t >> 1;
      mlout[((sidx * 4 + cc) * B_ + b) * 2 + (t & 1)] = mlL[cc][t & 1];
    }
    __syncthreads();   // ered/wgt reuse in next unit
  }
}

// ---------------- flash combine + h_new GEMV ----------------
__global__ __launch_bounds__(256) void combine_hnew(
    const float* __restrict__ ctxp, const float* __restrict__ mlout,
    const float* __restrict__ xWih, const float* __restrict__ W_hh,
    float* __restrict__ out_h, __bf16* __restrict__ hn) {
  const int b = blockIdx.x, h = threadIdx.x;
  __shared__ float cs[H_];
  float M = -3.4e38f;
#pragma unroll
  for (int cc = 0; cc < NCHK; ++cc) M = fmaxf(M, mlout[(cc * B_ + b) * 2]);
  float num = 0.f, den = 0.f;
#pragma unroll
  for (int cc = 0; cc < NCHK; ++cc) {
    const float mw = __expf(mlout[(cc * B_ + b) * 2] - M);
    den = fmaf(mw, mlout[(cc * B_ + b) * 2 + 1], den);
    num = fmaf(mw, ctxp[((size_t)cc * B_ + b) * H_ + h], num);
  }
  cs[h] = num / den;
  __syncthreads();
  const float* __restrict__ wr = W_hh + (size_t)h * H_;
  float a = xWih[b * H_ + h];
  for (int k = 0; k < H_; k += 4) {
    const float4 w4 = *reinterpret_cast<const float4*>(wr + k);
    const float4 c4 = *reinterpret_cast<const float4*>(&cs[k]);
    a = fmaf(c4.x, w4.x, a); a = fmaf(c4.y, w4.y, a);
    a = fmaf(c4.z, w4.z, a); a = fmaf(c4.w, w4.w, a);
  }
  const float hv = fast_tanh(a);
  out_h[b * H_ + h] = hv;
  hn[b * H_ + h] = (__bf16)hv;
}

// ---------------- logits = h_new @ W_out^T + b_out via pure-bf16 MFMA ----------------
__global__ __launch_bounds__(256) void logits_mfma(
    const float* __restrict__ Wout, const float* __restrict__ bout,
    const __bf16* __restrict__ hn, float* __restrict__ logits) {
  const int v0 = blockIdx.x * 64;
  const int t = threadIdx.x;
  const int wv = t >> 6, l = t & 63, l15 = l & 15, lg = l >> 4;

  __shared__ __bf16 Wsub[8][64][32];   // 32 KB, slot-rotated layout

  {
    const int srow = t >> 2, sg = t & 3;
    const int wslot = (sg + (srow >> 1)) & 3;
    const int vc = (v0 + srow) < V_ ? (v0 + srow) : (V_ - 1);
    const float* __restrict__ wr = Wout + (size_t)vc * H_ + sg * 8;
#pragma unroll
    for (int ks = 0; ks < 8; ++ks) {
      const float4 f0 = *reinterpret_cast<const float4*>(wr + ks * 32);
      const float4 f1 = *reinterpret_cast<const float4*>(wr + ks * 32 + 4);
      const float xv[8] = {f0.x, f0.y, f0.z, f0.w, f1.x, f1.y, f1.z, f1.w};
      bf16x8 h8;
#pragma unroll
      for (int j = 0; j < 8; ++j) h8[j] = (__bf16)xv[j];
      *reinterpret_cast<bf16x8*>(&Wsub[ks][srow][wslot * 8]) = h8;
    }
  }
  __syncthreads();

  f32x4 acc[4];
#pragma unroll
  for (int i = 0; i < 4; ++i) acc[i] = (f32x4)(0.f);
  const int colb = wv * 16 + l15;   // batch col
#pragma unroll
  for (int k = 0; k < 8; ++k) {
    const bf16x8 bfrag = *reinterpret_cast<const bf16x8*>(hn + (size_t)colb * H_ + k * 32 + lg * 8);
    bf16x8 ah[4];
#pragma unroll
    for (int rf = 0; rf < 4; ++rf) {
      const int rr = rf * 16 + l15;
      const int slot = (lg + (rr >> 1)) & 3;
      ah[rf] = *reinterpret_cast<const bf16x8*>(&Wsub[k][rr][slot * 8]);
    }
#pragma unroll
    for (int rf = 0; rf < 4; ++rf)
      acc[rf] = mfma16(ah[rf], bfrag, acc[rf]);
  }
#pragma unroll
  for (int rf = 0; rf < 4; ++rf) {
    const int v = v0 + rf * 16 + lg * 4;
    if (v < V_) {
      const float4 bo = *reinterpret_cast<const float4*>(bout + v);
      float4 o;
      o.x = acc[rf][0] + bo.x; o.y = acc[rf][1] + bo.y;
      o.z = acc[rf][2] + bo.z; o.w = acc[rf][3] + bo.w;
      *reinterpret_cast<float4*>(logits + (size_t)colb * V_ + v) = o;
    }
  }
}

extern "C" void kernel_launch(void* const* d_in, const int* in_sizes, int n_in,
                              void* d_out, int out_size, void* d_ws, size_t ws_size,
                              hipStream_t stream) {
  const int*   inp  = (const int*)  d_in[0];
  const float* enc  = (const float*)d_in[2];
  const float* emb  = (const float*)d_in[3];
  const float* U    = (const float*)d_in[4];
  const float* W    = (const float*)d_in[5];
  const float* v    = (const float*)d_in[6];
  const float* W_ih = (const float*)d_in[7];
  const float* W_hh = (const float*)d_in[8];
  const float* b_ih = (const float*)d_in[9];
  const float* b_hh = (const float*)d_in[10];
  const float* Wout = (const float*)d_in[11];
  const float* bout = (const float*)d_in[12];

  float* logits = (float*)d_out;
  float* out_h  = logits + (size_t)B_ * V_;

  float* ws    = (float*)d_ws;
  __bf16* wt2  = (__bf16*)ws;                       // 65536 bf16 = 128 KB
  float* xU    = ws + 32768;                        // after 128 KB
  float* xWih  = xU + B_ * H_;
  float* ctxp  = xWih + B_ * H_;                    // NCHK*B*H
  float* mlout = ctxp + (size_t)NCHK * B_ * H_;     // NCHK*B*2
  __bf16* hn   = (__bf16*)(mlout + NCHK * B_ * 2);  // B*H bf16

  prep_k<<<dim3(B_), dim3(256), 0, stream>>>(inp, emb, U, W_ih, b_ih, b_hh, xU, xWih);
  prep_w<<<dim3(H_ * H_ / 256), dim3(256), 0, stream>>>(W, wt2);
  attn_fused<<<dim3(256), dim3(512), 0, stream>>>(enc, wt2, xU, v, ctxp, mlout);
  combine_hnew<<<dim3(B_), dim3(256), 0, stream>>>(ctxp, mlout, xWih, W_hh, out_h, hn);
  logits_mfma<<<dim3((V_ + 63) / 64), dim3(256), 0, stream>>>(Wout, bout, hn, logits);
}